// Round 1
// baseline (254.344 us; speedup 1.0000x reference)
//
#include <hip/hip_runtime.h>

// BSplineBasis: x[1048576], knots[64] (clamped cubic, 57 uniform interior
// intervals) -> out[1048576, 60] float32.
//
// R7: 512 rows/block (2 rows/thread, float2 x-load), 2048 blocks.
//  - Halves the total per-block fixed cost (redundant 256-partial min/max
//    reduce ~350cy, knots LDS load, phase-1 start bubble) and halves block
//    turnover: at <=64 VGPR this is exactly 8 blocks/CU = ONE residency
//    generation (no second scheduling round / tail).
//  - k1 partials now interleaved (mn,mx) pairs -> k2 reduce does one float2
//    load (one L2 round-trip) instead of two dependent scalar loads.
//  - Everything else is the R5 best-measured structure (251.1 -> 249.3 us):
//    local de Boor triangle (~30 VALU/row, only 4 of 60 basis values are
//    nonzero for a cubic), LDS-staged fully-coalesced phase-2 write-out
//    (contiguous float4s, 16 lines/wave-store).
//
// Measurement context (R0 counters): the top-5 dispatches are ALL harness
// poison fills (960 MiB d_ws ~151us + 240 MiB d_out ~37us per replay, at
// 82-84% HBM peak) — ~188us of dur_us is untouchable. Controllable slice is
// ~61us vs a ~43us floor (240 MiB out @ 6.6 TB/s + 2 launches).
//
// Reference quirk we must reproduce: xn = (x - min)/(max - min + 1e-8) in
// fp32 loses the 1e-8 (range ~9.7, ulp ~1e-6), so the max element has
// xn == 1.0 exactly. The reference's half-open degree-0 indicator
// (x >= t[j]) & (x < t[j+1]) then yields an ALL-ZERO row for that element.
//
// Workspace (floats): [0..511] interleaved (min,max) pairs per k1 block (2 KB).

#define N_BASIS 60

__device__ __forceinline__ float fast_rcp(float a) {
    return __builtin_amdgcn_rcpf(a);  // ~1 ulp; harness threshold ~2e-2, fine
}

// ---------------- Kernel 1: per-block partial min/max ----------------
__global__ __launch_bounds__(256) void k_partial_minmax(
    const float* __restrict__ x, float* __restrict__ ws, int n4) {
    const int tid = threadIdx.x;
    int gid = blockIdx.x * 256 + tid;
    const int stride = gridDim.x * 256;
    const float4* __restrict__ x4 = (const float4*)x;

    float mn = 3.4028235e38f, mx = -3.4028235e38f;
    for (int i = gid; i < n4; i += stride) {
        float4 v = x4[i];
        mn = fminf(mn, fminf(fminf(v.x, v.y), fminf(v.z, v.w)));
        mx = fmaxf(mx, fmaxf(fmaxf(v.x, v.y), fmaxf(v.z, v.w)));
    }
#pragma unroll
    for (int off = 32; off > 0; off >>= 1) {
        mn = fminf(mn, __shfl_down(mn, off, 64));
        mx = fmaxf(mx, __shfl_down(mx, off, 64));
    }
    __shared__ float smn[4], smx[4];
    if ((tid & 63) == 0) { smn[tid >> 6] = mn; smx[tid >> 6] = mx; }
    __syncthreads();
    if (tid == 0) {
        mn = fminf(fminf(smn[0], smn[1]), fminf(smn[2], smn[3]));
        mx = fmaxf(fmaxf(smx[0], smx[1]), fmaxf(smx[2], smx[3]));
        ws[2 * blockIdx.x] = mn;       // interleaved pair -> one float2 load
        ws[2 * blockIdx.x + 1] = mx;   // in k2's redundant reduce
    }
}

// ---- local de Boor (Piegl-Tiller A2.2), cubic: 4 nonzero basis values ----
__device__ __forceinline__ void eval_row(float xn, const float* __restrict__ t,
                                         float4& Nv, int& base) {
    // Half-open indicator: xn >= 1.0 (the max element) -> all-zero row.
    const bool live = (xn < 1.0f) && (xn >= 0.0f);

    // Interval i with t[i] <= xn < t[i+1]; interior intervals are uniform
    // width ~1/57 starting at t[3]=0: floor guess, adjust vs actual knots.
    int ii = (int)(xn * 57.0f);
    ii = ii < 0 ? 0 : (ii > 56 ? 56 : ii);
    int i = ii + 3;
    if (xn < t[i]) i -= 1;
    else if (xn >= t[i + 1]) i += 1;
    i = i < 3 ? 3 : (i > 59 ? 59 : i);

    const float l1 = xn - t[i];
    const float l2 = xn - t[i - 1];
    const float l3 = xn - t[i - 2];
    const float r1 = t[i + 1] - xn;
    const float r2 = t[i + 2] - xn;
    const float r3 = t[i + 3] - xn;

    float N0 = 1.0f, N1, N2, N3, temp, saved;
    // d = 1
    temp = N0 * fast_rcp(r1 + l1);
    N0 = r1 * temp;
    N1 = l1 * temp;
    // d = 2
    temp = N0 * fast_rcp(r1 + l2);
    N0 = r1 * temp;
    saved = l2 * temp;
    temp = N1 * fast_rcp(r2 + l1);
    N1 = saved + r2 * temp;
    N2 = l1 * temp;
    // d = 3
    temp = N0 * fast_rcp(r1 + l3);
    N0 = r1 * temp;
    saved = l3 * temp;
    temp = N1 * fast_rcp(r2 + l2);
    N1 = saved + r2 * temp;
    saved = l2 * temp;
    temp = N2 * fast_rcp(r3 + l1);
    N2 = saved + r3 * temp;
    N3 = l1 * temp;

    const float g = live ? 1.0f : 0.0f;  // zero the boundary row
    Nv.x = N0 * g; Nv.y = N1 * g; Nv.z = N2 * g; Nv.w = N3 * g;
    base = i - 3;  // 0..56
}

// ---------------- Kernel 2: fused final-reduce + main ----------------
// Grid must be exactly nrows/512 blocks (nrows = 1048576 -> 2048 blocks).
__global__ __launch_bounds__(256) void k_bspline(
    const float* __restrict__ x, const float* __restrict__ knots,
    const float* __restrict__ ws, float* __restrict__ out) {
    __shared__ float t[64];
    __shared__ float4 sN[512];   // 4 nonzero basis values per row
    __shared__ int sBase[512];   // first nonzero column per row
    __shared__ float smn[4], smx[4];
    __shared__ float sParam[2];  // xmin, range

    const int tid = threadIdx.x;
    if (tid < 64) t[tid] = knots[tid];

    // ---- Redundant final min/max reduce (2 KB of L2-hot partials) ----
    {
        const float2 p = ((const float2*)ws)[tid];
        float mn = p.x;
        float mx = p.y;
#pragma unroll
        for (int off = 32; off > 0; off >>= 1) {
            mn = fminf(mn, __shfl_down(mn, off, 64));
            mx = fmaxf(mx, __shfl_down(mx, off, 64));
        }
        if ((tid & 63) == 0) { smn[tid >> 6] = mn; smx[tid >> 6] = mx; }
        __syncthreads();
        if (tid == 0) {
            mn = fminf(fminf(smn[0], smn[1]), fminf(smn[2], smn[3]));
            mx = fmaxf(fmaxf(smx[0], smx[1]), fmaxf(smx[2], smx[3]));
            sParam[0] = mn;
            // fp32 add, same as the fp32 reference: the 1e-8 is rounded away
            // for range ~9.7 -> max element normalizes to exactly 1.0.
            sParam[1] = (mx - mn) + 1e-8f;
        }
        __syncthreads();
    }
    const float xmin = sParam[0];
    const float range = sParam[1];

    // ---- Phase 1: one thread = two adjacent rows (one float2 load) ----
    const float2 xv = ((const float2*)x)[blockIdx.x * 256 + tid];
    const float rr = fast_rcp(range) * range;  // keep div semantics exact:
    (void)rr;  // (not used — division below must bitwise-match the ref)

    float4 Na, Nb;
    int ba, bb;
    eval_row((xv.x - xmin) / range, t, Na, ba);  // fp32 div, matches ref
    eval_row((xv.y - xmin) / range, t, Nb, bb);

    sN[2 * tid] = Na;
    sN[2 * tid + 1] = Nb;
    sBase[2 * tid] = ba;
    sBase[2 * tid + 1] = bb;
    __syncthreads();

    // ---- Phase 2: cooperative, fully-coalesced write-out ----
    // Block's span: 512 rows * 15 float4 = 7680 contiguous float4s.
    // Thread tid writes p = tid + it*256 -> consecutive lanes, consecutive
    // float4s: 1 KB per wave-store, 16 cache lines (vs 64 strided).
    // Incremental (r,j): p+256 -> r+=17, j+=1, carry when j wraps past 14
    // (256 = 17*15 + 1).
    float4* __restrict__ o4 = (float4*)out + (size_t)blockIdx.x * 7680;
    int r = (unsigned)tid / 15u;
    int j = tid - r * 15;
#pragma unroll
    for (int it = 0; it < 30; ++it) {
        const float4 N = sN[r];  // <=5 distinct rows per wave (2-way free)
        const int b = sBase[r];
        const int d0 = (j << 2) - b;
        float4 v;
        v.x = (d0 == 0) ? N.x : (d0 == 1) ? N.y : (d0 == 2) ? N.z : (d0 == 3) ? N.w : 0.0f;
        const int d1 = d0 + 1;
        v.y = (d1 == 0) ? N.x : (d1 == 1) ? N.y : (d1 == 2) ? N.z : (d1 == 3) ? N.w : 0.0f;
        const int d2 = d0 + 2;
        v.z = (d2 == 0) ? N.x : (d2 == 1) ? N.y : (d2 == 2) ? N.z : (d2 == 3) ? N.w : 0.0f;
        const int d3 = d0 + 3;
        v.w = (d3 == 0) ? N.x : (d3 == 1) ? N.y : (d3 == 2) ? N.z : (d3 == 3) ? N.w : 0.0f;
        o4[tid + it * 256] = v;
        r += 17; j += 1;
        if (j >= 15) { j -= 15; r += 1; }
    }
}

extern "C" void kernel_launch(void* const* d_in, const int* in_sizes, int n_in,
                              void* d_out, int out_size, void* d_ws, size_t ws_size,
                              hipStream_t stream) {
    const float* x = (const float*)d_in[0];
    const float* knots = (const float*)d_in[1];
    float* out = (float*)d_out;
    float* ws = (float*)d_ws;
    const int nrows = in_sizes[0];

    k_partial_minmax<<<256, 256, 0, stream>>>(x, ws, nrows / 4);
    k_bspline<<<nrows / 512, 256, 0, stream>>>(x, knots, ws, out);
}

// Round 2
// 250.537 us; speedup vs baseline: 1.0152x; 1.0152x over previous
//
#include <hip/hip_runtime.h>

// BSplineBasis: x[1048576], knots[64] (clamped cubic, 57 uniform interior
// intervals) -> out[1048576, 60] float32.
//
// R8: revert to the R6 best-measured structure (4096 blocks, 1 row/thread,
// 249.3 us). R7's 512-row/2-rows-per-thread variant regressed +5 us (likely
// VGPR cliff -> blocks/CU drop; per-block fixed cost is NOT the bottleneck).
// Kept from R7: k1 writes interleaved (mn,mx) pairs -> k2's redundant reduce
// does one float2 load instead of two dependent scalar loads.
// New in R8: x[row] load hoisted above the ws-reduce so its HBM latency
// overlaps the reduce's L2 round-trip + shuffle chain (it previously sat on
// the critical path after the second barrier).
//
// Structure (R2-R5 ladder, all counter-verified):
//  - Only 4 of 60 basis values are nonzero per row (cubic local support):
//    local de Boor triangle (Piegl-Tiller A2.2), ~30 VALU ops/row.
//  - Phase 2 writes the block's 3840 contiguous float4s lane-consecutive
//    (fully coalesced, 16 lines/wave-store). Naive per-row strided write
//    was 64 lines/wave-store and cost ~70 us (R2->R3).
//  - 4096 independent blocks: cooperative single-kernel fusion (R4) lost 2x
//    from TLP starvation; 512-row blocks (R7) lost 5 us. Final min/max
//    reduce stays fused into the main kernel's head (redundant per-block
//    reduce of 256 L2-hot partial pairs).
//
// Measurement context: top-5 dispatches are ALL harness poison fills
// (960 MiB d_ws ~151 us + 240 MiB d_out ~37 us per replay at 82-84% HBM
// peak) — ~188 us of dur_us is untouchable. Controllable slice ~61 us vs
// ~45 us floor (240 MiB out + 12 MiB in @ 6.6 TB/s + 2 launches).
//
// Reference quirk we must reproduce: xn = (x - min)/(max - min + 1e-8) in
// fp32 loses the 1e-8 (range ~9.7, ulp ~1e-6), so the max element has
// xn == 1.0 exactly. The reference's half-open degree-0 indicator
// (x >= t[j]) & (x < t[j+1]) then yields an ALL-ZERO row for that element.
//
// Workspace (floats): [0..511] interleaved (min,max) pairs per k1 block (2 KB).

#define N_BASIS 60

__device__ __forceinline__ float fast_rcp(float a) {
    return __builtin_amdgcn_rcpf(a);  // ~1 ulp; harness threshold ~2e-2, fine
}

// ---------------- Kernel 1: per-block partial min/max ----------------
__global__ __launch_bounds__(256) void k_partial_minmax(
    const float* __restrict__ x, float* __restrict__ ws, int n4) {
    const int tid = threadIdx.x;
    int gid = blockIdx.x * 256 + tid;
    const int stride = gridDim.x * 256;
    const float4* __restrict__ x4 = (const float4*)x;

    float mn = 3.4028235e38f, mx = -3.4028235e38f;
    for (int i = gid; i < n4; i += stride) {
        float4 v = x4[i];
        mn = fminf(mn, fminf(fminf(v.x, v.y), fminf(v.z, v.w)));
        mx = fmaxf(mx, fmaxf(fmaxf(v.x, v.y), fmaxf(v.z, v.w)));
    }
#pragma unroll
    for (int off = 32; off > 0; off >>= 1) {
        mn = fminf(mn, __shfl_down(mn, off, 64));
        mx = fmaxf(mx, __shfl_down(mx, off, 64));
    }
    __shared__ float smn[4], smx[4];
    if ((tid & 63) == 0) { smn[tid >> 6] = mn; smx[tid >> 6] = mx; }
    __syncthreads();
    if (tid == 0) {
        mn = fminf(fminf(smn[0], smn[1]), fminf(smn[2], smn[3]));
        mx = fmaxf(fmaxf(smx[0], smx[1]), fmaxf(smx[2], smx[3]));
        ws[2 * blockIdx.x] = mn;       // interleaved pair -> one float2 load
        ws[2 * blockIdx.x + 1] = mx;   // in k2's redundant reduce
    }
}

// ---------------- Kernel 2: fused final-reduce + main ----------------
// Grid must be exactly nrows/256 blocks (nrows = 1048576 -> 4096 blocks).
__global__ __launch_bounds__(256) void k_bspline(
    const float* __restrict__ x, const float* __restrict__ knots,
    const float* __restrict__ ws, float* __restrict__ out) {
    __shared__ float t[64];
    __shared__ float4 sN[256];   // 4 nonzero basis values per row
    __shared__ int sBase[256];   // first nonzero column per row
    __shared__ float smn[4], smx[4];
    __shared__ float sParam[2];  // xmin, range

    const int tid = threadIdx.x;

    // Issue the row's x load FIRST: its HBM latency overlaps the entire
    // ws-reduce below (the value isn't consumed until after the 2nd barrier).
    const int row = blockIdx.x * 256 + tid;
    const float xval = x[row];

    if (tid < 64) t[tid] = knots[tid];

    // ---- Redundant final min/max reduce (2 KB of L2-hot partial pairs) ----
    {
        const float2 p = ((const float2*)ws)[tid];
        float mn = p.x;
        float mx = p.y;
#pragma unroll
        for (int off = 32; off > 0; off >>= 1) {
            mn = fminf(mn, __shfl_down(mn, off, 64));
            mx = fmaxf(mx, __shfl_down(mx, off, 64));
        }
        if ((tid & 63) == 0) { smn[tid >> 6] = mn; smx[tid >> 6] = mx; }
        __syncthreads();
        if (tid == 0) {
            mn = fminf(fminf(smn[0], smn[1]), fminf(smn[2], smn[3]));
            mx = fmaxf(fmaxf(smx[0], smx[1]), fmaxf(smx[2], smx[3]));
            sParam[0] = mn;
            // fp32 add, same as the fp32 reference: the 1e-8 is rounded away
            // for range ~9.7 -> max element normalizes to exactly 1.0.
            sParam[1] = (mx - mn) + 1e-8f;
        }
        __syncthreads();
    }
    const float xmin = sParam[0];
    const float range = sParam[1];

    // ---- Phase 1: one thread = one row; local de Boor (P-T A2.2) ----
    const float xn = (xval - xmin) / range;  // fp32 div, bitwise-matches ref

    // Half-open indicator: xn >= 1.0 (the max element) -> all-zero row.
    const bool live = (xn < 1.0f) && (xn >= 0.0f);

    // Interval i with t[i] <= xn < t[i+1]; interior intervals are uniform
    // width ~1/57 starting at t[3]=0: floor guess, adjust vs actual knots.
    int ii = (int)(xn * 57.0f);
    ii = ii < 0 ? 0 : (ii > 56 ? 56 : ii);
    int i = ii + 3;
    if (xn < t[i]) i -= 1;
    else if (xn >= t[i + 1]) i += 1;
    i = i < 3 ? 3 : (i > 59 ? 59 : i);

    const float l1 = xn - t[i];
    const float l2 = xn - t[i - 1];
    const float l3 = xn - t[i - 2];
    const float r1 = t[i + 1] - xn;
    const float r2 = t[i + 2] - xn;
    const float r3 = t[i + 3] - xn;

    float N0 = 1.0f, N1, N2, N3, temp, saved;
    // d = 1
    temp = N0 * fast_rcp(r1 + l1);
    N0 = r1 * temp;
    N1 = l1 * temp;
    // d = 2
    temp = N0 * fast_rcp(r1 + l2);
    N0 = r1 * temp;
    saved = l2 * temp;
    temp = N1 * fast_rcp(r2 + l1);
    N1 = saved + r2 * temp;
    N2 = l1 * temp;
    // d = 3
    temp = N0 * fast_rcp(r1 + l3);
    N0 = r1 * temp;
    saved = l3 * temp;
    temp = N1 * fast_rcp(r2 + l2);
    N1 = saved + r2 * temp;
    saved = l2 * temp;
    temp = N2 * fast_rcp(r3 + l1);
    N2 = saved + r3 * temp;
    N3 = l1 * temp;

    const float g = live ? 1.0f : 0.0f;  // zero the boundary row
    float4 Nv;
    Nv.x = N0 * g; Nv.y = N1 * g; Nv.z = N2 * g; Nv.w = N3 * g;
    sN[tid] = Nv;
    sBase[tid] = i - 3;  // 0..56
    __syncthreads();

    // ---- Phase 2: cooperative, fully-coalesced write-out ----
    // Block's span: 256 rows * 15 float4 = 3840 contiguous float4s.
    // Thread tid writes p = tid + it*256 -> consecutive lanes, consecutive
    // float4s: 1 KB per wave-store, 16 cache lines (vs 64 strided).
    // Incremental (r,j): p+256 -> r+=17, j+=1, carry when j wraps past 14
    // (256 = 17*15 + 1).
    float4* __restrict__ o4 = (float4*)out + (size_t)blockIdx.x * 3840;
    int r = (unsigned)tid / 15u;
    int j = tid - r * 15;
#pragma unroll
    for (int it = 0; it < 15; ++it) {
        const float4 N = sN[r];  // <=5 distinct rows per wave (2-way free)
        const int b = sBase[r];
        const int d0 = (j << 2) - b;
        float4 v;
        v.x = (d0 == 0) ? N.x : (d0 == 1) ? N.y : (d0 == 2) ? N.z : (d0 == 3) ? N.w : 0.0f;
        const int d1 = d0 + 1;
        v.y = (d1 == 0) ? N.x : (d1 == 1) ? N.y : (d1 == 2) ? N.z : (d1 == 3) ? N.w : 0.0f;
        const int d2 = d0 + 2;
        v.z = (d2 == 0) ? N.x : (d2 == 1) ? N.y : (d2 == 2) ? N.z : (d2 == 3) ? N.w : 0.0f;
        const int d3 = d0 + 3;
        v.w = (d3 == 0) ? N.x : (d3 == 1) ? N.y : (d3 == 2) ? N.z : (d3 == 3) ? N.w : 0.0f;
        o4[tid + it * 256] = v;
        r += 17; j += 1;
        if (j >= 15) { j -= 15; r += 1; }
    }
}

extern "C" void kernel_launch(void* const* d_in, const int* in_sizes, int n_in,
                              void* d_out, int out_size, void* d_ws, size_t ws_size,
                              hipStream_t stream) {
    const float* x = (const float*)d_in[0];
    const float* knots = (const float*)d_in[1];
    float* out = (float*)d_out;
    float* ws = (float*)d_ws;
    const int nrows = in_sizes[0];

    k_partial_minmax<<<256, 256, 0, stream>>>(x, ws, nrows / 4);
    k_bspline<<<nrows / 256, 256, 0, stream>>>(x, knots, ws, out);
}